// Round 1
// 22626.846 us; speedup vs baseline: 1.0006x; 1.0006x over previous
//
#include <hip/hip_runtime.h>
#include <stdint.h>

typedef unsigned short us;
using bf16x8 = __attribute__((ext_vector_type(8))) __bf16;
using f32x4  = __attribute__((ext_vector_type(4))) float;

__device__ __forceinline__ float bf2f(us x) {
    union { unsigned u; float f; } v; v.u = ((unsigned)x) << 16; return v.f;
}
__device__ __forceinline__ us f2bf(float f) {
    union { float f; unsigned u; } v; v.f = f;
    unsigned u = v.u;
    u += 0x7FFFu + ((u >> 16) & 1u);   // RNE
    return (us)(u >> 16);
}
__device__ __forceinline__ float ldin(const void* p, size_t i, int f) {
    return f ? ((const float*)p)[i] : bf2f(((const us*)p)[i]);
}

__device__ __forceinline__ void gload_lds16(const void* g, void* l) {
    __builtin_amdgcn_global_load_lds(
        (const __attribute__((address_space(1))) void*)g,
        (__attribute__((address_space(3))) void*)l, 16, 0, 0);
}

// ------------------------------------------------------------------
// Dtype probe (unchanged): bf16 NaN/Inf patterns appear iff buffer is fp32.
// ------------------------------------------------------------------
__global__ void detect_dtype(const us* __restrict__ x, int* __restrict__ flag)
{
    __shared__ int cnt;
    if (threadIdx.x == 0) cnt = 0;
    __syncthreads();
    int c = 0;
    for (int i = threadIdx.x; i < 32768; i += 256) {
        us u = x[i];
        if ((u & 0x7F80u) == 0x7F80u) c++;
    }
    atomicAdd(&cnt, c);
    __syncthreads();
    if (threadIdx.x == 0) *flag = (cnt > 0) ? 1 : 0;
}

// ------------------------------------------------------------------
// 32x32 LDS-tiled bf16 transpose: out[C][R] = in[R][C]^T. Runs once, bf16 only.
// ------------------------------------------------------------------
__global__ __launch_bounds__(256)
void transpose_bf16(const us* __restrict__ in, us* __restrict__ out,
                    int R, int C, const int* __restrict__ flag)
{
    if (*flag) return;
    __shared__ us tile[32][33];
    const int tc = C >> 5;
    const int br = blockIdx.x / tc, bc = blockIdx.x % tc;
    const int tx = threadIdx.x & 31, ty = threadIdx.x >> 5;
    #pragma unroll
    for (int i = 0; i < 32; i += 8)
        tile[ty + i][tx] = in[(size_t)(br * 32 + ty + i) * C + bc * 32 + tx];
    __syncthreads();
    #pragma unroll
    for (int i = 0; i < 32; i += 8)
        out[(size_t)(bc * 32 + ty + i) * R + br * 32 + tx] = tile[tx][ty + i];
}

// ------------------------------------------------------------------
// MFMA GEMM core: C128x64 tile = A[M][KA] @ Bt[N][KB]^T, bf16 in, fp32 acc.
// 4 waves (2x2), each wave 64x32 -> acc[4][2] f32x4.
// LDS: A 128x64 (row=128B), B 64x64; XOR-swizzle byte^=((row&7)<<4) applied
// by pre-swizzling the global_load_lds SOURCE chunk (LDS dest stays linear,
// m104/m173 rule) and the same XOR on the ds_read side (T2).
// A and B fragments use identical per-lane k-ordering, so any intra-lane
// k-permutation cancels in the MFMA dot product.
// ------------------------------------------------------------------
__device__ __forceinline__ void mfma_gemm_core(
    const us* __restrict__ A, size_t lda, size_t arow0,
    const us* __restrict__ Bt, size_t ldb,
    int KA, int KB, int tile_m, int tile_n,
    us* Alds, us* Blds, f32x4 (&acc)[4][2])
{
    const int t = threadIdx.x;
    const int w = t >> 6, l = t & 63;
    const int lr = l & 15, lg = l >> 4;
    const int rsub = l >> 3;                    // row-in-instruction 0..7
    const int cs = (l & 7) ^ ((l >> 3) & 7);    // pre-swizzled source chunk
    const size_t arowbase = arow0 + (size_t)tile_m * 128;
    const size_t nbase = (size_t)tile_n * 64;
    const int wm = w >> 1, wn = w & 1;

    #pragma unroll
    for (int m = 0; m < 4; ++m)
        #pragma unroll
        for (int n = 0; n < 2; ++n) {
            const f32x4 z = {0.f, 0.f, 0.f, 0.f};
            acc[m][n] = z;
        }

    for (int kt = 0; kt < KA; kt += 64) {
        int bk = kt; if (bk >= KB) bk -= KB;    // proj: lo-plane reuses Bt
        __syncthreads();                        // prev tile fully consumed
        // stage A: 16KB = 16 wave-instructions, 4 per wave
        #pragma unroll
        for (int j = 0; j < 4; ++j) {
            const int inst = w * 4 + j;
            const int r = inst * 8 + rsub;
            gload_lds16(A + (arowbase + r) * lda + kt + cs * 8,
                        Alds + inst * 512);
        }
        // stage B: 8KB = 8 wave-instructions, 2 per wave
        #pragma unroll
        for (int j = 0; j < 2; ++j) {
            const int inst = w * 2 + j;
            const int r = inst * 8 + rsub;
            gload_lds16(Bt + (nbase + r) * ldb + bk + cs * 8,
                        Blds + inst * 512);
        }
        __syncthreads();                        // drains vmcnt before barrier
        #pragma unroll
        for (int kk = 0; kk < 2; ++kk) {        // two K=32 MFMA steps
            bf16x8 af[4], bfr[2];
            #pragma unroll
            for (int m = 0; m < 4; ++m) {
                const int r = wm * 64 + m * 16 + lr;
                const int chunk = ((kk * 4) + lg) ^ (lr & 7);
                af[m] = *(const bf16x8*)(Alds + r * 64 + chunk * 8);
            }
            #pragma unroll
            for (int n = 0; n < 2; ++n) {
                const int r = wn * 32 + n * 16 + lr;
                const int chunk = ((kk * 4) + lg) ^ (lr & 7);
                bfr[n] = *(const bf16x8*)(Blds + r * 64 + chunk * 8);
            }
            #pragma unroll
            for (int m = 0; m < 4; ++m)
                #pragma unroll
                for (int n = 0; n < 2; ++n)
                    acc[m][n] = __builtin_amdgcn_mfma_f32_16x16x32_bf16(
                        af[m], bfr[n], acc[m][n], 0, 0, 0);
        }
    }
}

// qkv = x @ W_qkv^T(t) + b ; fp32 out into workspace. bf16 path only.
__global__ __launch_bounds__(256)
void mfma_gemm_qkv(const us* __restrict__ x, const us* __restrict__ Wt,
                   const us* __restrict__ bq, float* __restrict__ qkv,
                   const int* __restrict__ flag, size_t row0, int ntm)
{
    if (*flag) return;
    __shared__ us Alds[128 * 64];
    __shared__ us Blds[64 * 64];
    const int tile_m = blockIdx.x % ntm, tile_n = blockIdx.x / ntm;
    f32x4 acc[4][2];
    mfma_gemm_core(x, 768, row0, Wt, 768, 768, 768, tile_m, tile_n, Alds, Blds, acc);
    const int t = threadIdx.x, w = t >> 6, l = t & 63;
    const int lr = l & 15, lg = l >> 4;
    const int wm = w >> 1, wn = w & 1;
    #pragma unroll
    for (int n = 0; n < 2; ++n) {
        const int col = tile_n * 64 + wn * 32 + n * 16 + lr;
        const float bz = bf2f(bq[col]);
        #pragma unroll
        for (int m = 0; m < 4; ++m) {
            const int row = tile_m * 128 + wm * 64 + m * 16 + lg * 4;
            float* op = qkv + (size_t)row * 2496 + col;
            #pragma unroll
            for (int r = 0; r < 4; ++r)
                op[(size_t)r * 2496] = acc[m][n][r] + bz;
        }
    }
}

// out = xc(hi+lo planes) @ proj_W^T(t) + pb ; bf16 out. bf16 path only.
__global__ __launch_bounds__(256)
void mfma_gemm_proj(const us* __restrict__ xc16, const us* __restrict__ Pt,
                    const us* __restrict__ pb, us* __restrict__ out,
                    const int* __restrict__ flag, size_t row0, int ntm)
{
    if (*flag) return;
    __shared__ us Alds[128 * 64];
    __shared__ us Blds[64 * 64];
    const int tile_m = blockIdx.x % ntm, tile_n = blockIdx.x / ntm;
    f32x4 acc[4][2];
    mfma_gemm_core(xc16, 1664, 0, Pt, 832, 1664, 832, tile_m, tile_n, Alds, Blds, acc);
    const int t = threadIdx.x, w = t >> 6, l = t & 63;
    const int lr = l & 15, lg = l >> 4;
    const int wm = w >> 1, wn = w & 1;
    #pragma unroll
    for (int n = 0; n < 2; ++n) {
        const int col = tile_n * 64 + wn * 32 + n * 16 + lr;
        const float bz = bf2f(pb[col]);
        #pragma unroll
        for (int m = 0; m < 4; ++m) {
            const int row = tile_m * 128 + wm * 64 + m * 16 + lg * 4;
            us* op = out + (row0 + row) * 768 + col;
            #pragma unroll
            for (int r = 0; r < 4; ++r)
                op[(size_t)r * 768] = f2bf(acc[m][n][r] + bz);
        }
    }
}

// ------------------------------------------------------------------
// fp32 fallback GEMMs (run only when inputs are fp32)
// ------------------------------------------------------------------
__global__ __launch_bounds__(256)
void qkv_gemm_f32(const void* __restrict__ x, const void* __restrict__ W,
                  const void* __restrict__ bq, float* __restrict__ qkv,
                  const int* __restrict__ flag, size_t row0, int nrows)
{
    if (!*flag) return;
    const size_t tid = (size_t)blockIdx.x * 256 + threadIdx.x;
    if (tid >= (size_t)nrows * 2496) return;
    const int col = (int)(tid % 2496);
    const size_t row = tid / 2496;
    float acc = ((const float*)bq)[col];
    const float* xr = (const float*)x + (row0 + row) * 768;
    const float* Wp = (const float*)W + col;
    for (int k = 0; k < 768; k++) acc += xr[k] * Wp[(size_t)k * 2496];
    qkv[tid] = acc;
}

__global__ __launch_bounds__(256)
void proj_gemm_f32(const float* __restrict__ xc, const void* __restrict__ W,
                   const void* __restrict__ pb, void* __restrict__ out,
                   const int* __restrict__ flag, size_t row0, int nrows)
{
    if (!*flag) return;
    const size_t tid = (size_t)blockIdx.x * 256 + threadIdx.x;
    if (tid >= (size_t)nrows * 768) return;
    const int col = (int)(tid % 768);
    const size_t row = tid / 768;
    float acc = ((const float*)pb)[col];
    const float* xr = xc + row * 832;
    const float* Wp = (const float*)W + col;
    for (int j = 0; j < 832; j++) acc += xr[j] * Wp[(size_t)j * 768];
    ((float*)out)[(row0 + row) * 768 + col] = acc;
}

// ------------------------------------------------------------------
// r1,r2 = elementwise(z1,z2,v); thread per (bh, n, e)   (unchanged)
// ------------------------------------------------------------------
__global__ __launch_bounds__(256)
void zr_kernel(const float* __restrict__ qkv, const void* __restrict__ w1,
               const void* __restrict__ w2, float* __restrict__ r1,
               float* __restrict__ r2, const int* __restrict__ flag, int CB)
{
    const int f = *flag;
    const size_t tid = (size_t)blockIdx.x * 256 + threadIdx.x;
    if (tid >= (size_t)CB * 12 * 1024 * 64) return;
    const int e = (int)(tid & 63);
    const size_t rest = tid >> 6;
    const int n = (int)(rest & 1023);
    const int bh = (int)(rest >> 10);
    const int b = bh / 12, h = bh % 12;
    const float* krow = qkv + ((size_t)b * 1024 + n) * 2496 + 768 + h * 64;
    float z1 = 0.f, z2 = 0.f;
    if (f) {
        const float* w1p = (const float*)w1 + (size_t)h * 4096 + e;
        const float* w2p = (const float*)w2 + (size_t)h * 4096 + e;
        for (int d = 0; d < 64; d++) {
            const float kv = krow[d];
            z1 += kv * w1p[d * 64]; z2 += kv * w2p[d * 64];
        }
    } else {
        const us* w1p = (const us*)w1 + (size_t)h * 4096 + e;
        const us* w2p = (const us*)w2 + (size_t)h * 4096 + e;
        for (int d = 0; d < 64; d++) {
            const float kv = krow[d];
            z1 += kv * bf2f(w1p[d * 64]); z2 += kv * bf2f(w2p[d * 64]);
        }
    }
    const float vv = qkv[((size_t)b * 1024 + n) * 2496 + 1536 + h * 64 + e];
    const float ec = vv * (-1.0f / 3072.0f);
    const float sig = 1.f / (1.f + __expf(-z2));
    r1[tid] = ec * z2 * sig;
    r2[tid] = ec * z1 * (sig * (1.f + z2 * (1.f - sig)));
}

// ------------------------------------------------------------------
// grad update (unchanged)
// ------------------------------------------------------------------
__global__ __launch_bounds__(256)
void grad_update(const float* __restrict__ qkv, const float* __restrict__ r1,
                 const float* __restrict__ r2, const void* __restrict__ w1,
                 const void* __restrict__ w2, float* __restrict__ wu1,
                 float* __restrict__ wu2, const int* __restrict__ flag)
{
    const int f = *flag;
    const int bh = blockIdx.x, b = bh / 12, h = bh % 12;
    __shared__ float ks[64][64];
    __shared__ float gs[2][64][65];
    __shared__ float inv[2][64];
    const int t = threadIdx.x;
    const int e = t & 63, dq = t >> 6;
    float g1[16], g2[16];
    for (int i = 0; i < 16; i++) { g1[i] = 0.f; g2[i] = 0.f; }
    for (int ch = 0; ch < 16; ch++) {
        const int n0 = ch * 64;
        __syncthreads();
        for (int i = t; i < 4096; i += 256) {
            const int nn = i >> 6, dd = i & 63;
            ks[nn][dd] = qkv[((size_t)b * 1024 + n0 + nn) * 2496 + 768 + h * 64 + dd];
        }
        __syncthreads();
        const float* r1p = r1 + ((size_t)bh * 1024 + n0) * 64 + e;
        const float* r2p = r2 + ((size_t)bh * 1024 + n0) * 64 + e;
        for (int nn = 0; nn < 64; nn++) {
            const float rv1 = r1p[nn * 64], rv2 = r2p[nn * 64];
            for (int i = 0; i < 16; i++) {
                const float kv = ks[nn][dq + i * 4];
                g1[i] += kv * rv1; g2[i] += kv * rv2;
            }
        }
    }
    __syncthreads();
    for (int i = 0; i < 16; i++) { gs[0][dq + i * 4][e] = g1[i]; gs[1][dq + i * 4][e] = g2[i]; }
    __syncthreads();
    if (t < 128) {
        const int w = t >> 6, ee = t & 63;
        float s = 0.f;
        for (int d = 0; d < 64; d++) { const float g = gs[w][d][ee]; s += g * g; }
        inv[w][ee] = 1.f / (sqrtf(s) + 1.f);
    }
    __syncthreads();
    for (int i = t; i < 4096; i += 256) {
        const int d = i >> 6, ee = i & 63;
        const float w1v = ldin(w1, (size_t)h * 4096 + i, f);
        const float w2v = ldin(w2, (size_t)h * 4096 + i, f);
        wu1[(size_t)bh * 4096 + i] = w1v - gs[0][d][ee] * inv[0][ee];
        wu2[(size_t)bh * 4096 + i] = w2v - gs[1][d][ee] * inv[1][ee];
    }
}

// ------------------------------------------------------------------
// x1 = (q@wu1)*silu(q@wu2); bf16 mode stores hi+lo bf16 planes into xc16
// ------------------------------------------------------------------
__global__ __launch_bounds__(256)
void x1_kernel(const float* __restrict__ qkv, const float* __restrict__ wu1,
               const float* __restrict__ wu2, float* __restrict__ xc,
               const int* __restrict__ flag, int CB)
{
    const int f = *flag;
    const size_t tid = (size_t)blockIdx.x * 256 + threadIdx.x;
    if (tid >= (size_t)CB * 12 * 1024 * 64) return;
    const int e = (int)(tid & 63);
    const size_t rest = tid >> 6;
    const int n = (int)(rest & 1023);
    const int bh = (int)(rest >> 10);
    const int b = bh / 12, h = bh % 12;
    const float* qrow = qkv + ((size_t)b * 1024 + n) * 2496 + h * 64;
    const float* w1p = wu1 + (size_t)bh * 4096 + e;
    const float* w2p = wu2 + (size_t)bh * 4096 + e;
    float z1 = 0.f, z2 = 0.f;
    for (int d = 0; d < 64; d++) {
        const float qv = qrow[d];
        z1 += qv * w1p[d * 64]; z2 += qv * w2p[d * 64];
    }
    const float sig = 1.f / (1.f + __expf(-z2));
    const float val = z1 * z2 * sig;
    const size_t rb = (size_t)b * 1024 + n;
    const int c = h * 64 + e;
    if (f) {
        xc[rb * 832 + c] = val;
    } else {
        us* x16 = (us*)xc;
        const us hi = f2bf(val);
        x16[rb * 1664 + c] = hi;
        x16[rb * 1664 + 832 + c] = f2bf(val - bf2f(hi));
    }
}

// ------------------------------------------------------------------
// Depthwise 3x3 branch; bf16 mode stores hi+lo planes into xc16
// ------------------------------------------------------------------
__global__ __launch_bounds__(256)
void dwc_f32(const float* __restrict__ qkv, const void* __restrict__ w3,
             float* __restrict__ xc, const int* __restrict__ flag)
{
    const int f = *flag;
    __shared__ float qch[4][1026], kch[4][1026], vch[4][1026];
    __shared__ float w3s[4][12];
    const int b = blockIdx.x >> 4, dg = blockIdx.x & 15;
    const int t = threadIdx.x;
    for (int rr = 0; rr < 4; rr++) {
        const int n = t + rr * 256;
        const float* rp = qkv + ((size_t)b * 1024 + n) * 2496 + 2304 + dg * 4;
        for (int c = 0; c < 4; c++) {
            qch[c][n] = rp[c]; kch[c][n] = rp[64 + c]; vch[c][n] = rp[128 + c];
        }
    }
    __syncthreads();
    if (t < 128) {
        const int c = t >> 5, x = t & 31;
        float g[9];
        for (int i = 0; i < 9; i++) g[i] = 0.f;
        for (int y = 0; y < 32; y++) {
            const float e = vch[c][y * 32 + x] * (-1.0f / 3072.0f);
            for (int dy = -1; dy <= 1; dy++) {
                const int yy = y + dy;
                if (yy < 0 || yy > 31) continue;
                for (int dx = -1; dx <= 1; dx++) {
                    const int xx = x + dx;
                    if (xx < 0 || xx > 31) continue;
                    g[(dy + 1) * 3 + dx + 1] += kch[c][yy * 32 + xx] * e;
                }
            }
        }
        for (int m = 16; m >= 1; m >>= 1)
            for (int i = 0; i < 9; i++)
                g[i] += __shfl_xor(g[i], m, 64);
        if (x == 0) {
            float s = 0.f;
            for (int i = 0; i < 9; i++) s += g[i] * g[i];
            const float nrm = 1.f / (sqrtf(s) + 1.f);
            const int d = dg * 4 + c;
            for (int i = 0; i < 9; i++)
                w3s[c][i] = ldin(w3, (size_t)d * 9 + i, f) - g[i] * nrm;
        }
    }
    __syncthreads();
    for (int rr = 0; rr < 4; rr++) {
        const int n = t + rr * 256;
        const int y = n >> 5, xx = n & 31;
        for (int cc = 0; cc < 4; cc++) {
            float acc = 0.f;
            for (int ky = 0; ky < 3; ky++) {
                const int yy = y + ky - 1;
                if (yy < 0 || yy > 31) continue;
                for (int kx = 0; kx < 3; kx++) {
                    const int xz = xx + kx - 1;
                    if (xz < 0 || xz > 31) continue;
                    acc += qch[cc][yy * 32 + xz] * w3s[cc][ky * 3 + kx];
                }
            }
            const size_t rb = (size_t)b * 1024 + n;
            const int c = 768 + dg * 4 + cc;
            if (f) {
                xc[rb * 832 + c] = acc;
            } else {
                us* x16 = (us*)xc;
                const us hi = f2bf(acc);
                x16[rb * 1664 + c] = hi;
                x16[rb * 1664 + 832 + c] = f2bf(acc - bf2f(hi));
            }
        }
    }
}

// ------------------------------------------------------------------
// ws layout: [flag 256B][Wt 2496x768 bf16][Pt 768x832 bf16][CB region]
// CB unit fp32 elems: qkv 1024*2496 + r1/r2 2*786432 + wu 2*49152 + xc 851968
//   = 5,079,040  (xc fp32 region == 1024x1664 bf16 hi/lo region, same bytes)
// ------------------------------------------------------------------
extern "C" void kernel_launch(void* const* d_in, const int* in_sizes, int n_in,
                              void* d_out, int out_size, void* d_ws, size_t ws_size,
                              hipStream_t stream) {
    const void* x      = d_in[0];
    const void* W_qkv  = d_in[1];
    const void* b_qkv  = d_in[2];
    const void* w1     = d_in[3];
    const void* w2     = d_in[4];
    const void* w3     = d_in[5];
    const void* proj_W = d_in[6];
    const void* proj_b = d_in[7];

    int* flag = (int*)d_ws;
    char* wsB = (char*)d_ws + 256;
    us* Wt = (us*)wsB;                                   // 3,833,856 B
    us* Pt = (us*)(wsB + 2496 * 768 * 2);                // 1,277,952 B
    float* base = (float*)(wsB + 2496 * 768 * 2 + 768 * 832 * 2);

    const size_t per  = 5079040ULL;
    const size_t head = 256 + 2496 * 768 * 2 + 768 * 832 * 2;
    int CB = 1;
    for (int cand = 32; cand >= 1; cand >>= 1)
        if (head + per * cand * 4 <= ws_size) { CB = cand; break; }

    float* qkv_c = base;
    float* r1  = qkv_c + (size_t)CB * 1024 * 2496;
    float* r2  = r1  + (size_t)CB * 12 * 1024 * 64;
    float* wu1 = r2  + (size_t)CB * 12 * 1024 * 64;
    float* wu2 = wu1 + (size_t)CB * 12 * 4096;
    float* xc  = wu2 + (size_t)CB * 12 * 4096;

    detect_dtype<<<1, 256, 0, stream>>>((const us*)x, flag);
    // one-time weight transposes (bf16 path only; gated in-kernel)
    transpose_bf16<<<(768 / 32) * (2496 / 32), 256, 0, stream>>>(
        (const us*)W_qkv, Wt, 768, 2496, flag);
    transpose_bf16<<<(832 / 32) * (768 / 32), 256, 0, stream>>>(
        (const us*)proj_W, Pt, 832, 768, flag);

    const int passes = 32 / CB;
    const int nrows = CB * 1024;
    const int ntm = nrows / 128;
    for (int p = 0; p < passes; p++) {
        const size_t row0 = (size_t)p * CB * 1024;
        qkv_gemm_f32<<<(int)(((size_t)nrows * 2496 + 255) / 256), 256, 0, stream>>>(
            x, W_qkv, b_qkv, qkv_c, flag, row0, nrows);
        mfma_gemm_qkv<<<ntm * 39, 256, 0, stream>>>(
            (const us*)x, Wt, (const us*)b_qkv, qkv_c, flag, row0, ntm);
        zr_kernel<<<CB * 3072, 256, 0, stream>>>(qkv_c, w1, w2, r1, r2, flag, CB);
        grad_update<<<CB * 12, 256, 0, stream>>>(qkv_c, r1, r2, w1, w2, wu1, wu2, flag);
        x1_kernel<<<CB * 3072, 256, 0, stream>>>(qkv_c, wu1, wu2, xc, flag, CB);
        dwc_f32<<<CB * 16, 256, 0, stream>>>(qkv_c, w3, xc, flag);
        proj_gemm_f32<<<(int)(((size_t)nrows * 768 + 255) / 256), 256, 0, stream>>>(
            xc, proj_W, proj_b, d_out, flag, row0, nrows);
        mfma_gemm_proj<<<ntm * 12, 256, 0, stream>>>(
            (const us*)xc, Pt, (const us*)proj_b, (us*)d_out, flag, row0, ntm);
    }
}

// Round 2
// 2864.370 us; speedup vs baseline: 7.9038x; 7.8994x over previous
//
#include <hip/hip_runtime.h>
#include <stdint.h>

typedef unsigned short us;
using bf16x8 = __attribute__((ext_vector_type(8))) __bf16;
using f32x4  = __attribute__((ext_vector_type(4))) float;

__device__ __forceinline__ float bf2f(us x) {
    union { unsigned u; float f; } v; v.u = ((unsigned)x) << 16; return v.f;
}
__device__ __forceinline__ us f2bf(float f) {
    union { float f; unsigned u; } v; v.f = f;
    unsigned u = v.u;
    u += 0x7FFFu + ((u >> 16) & 1u);   // RNE
    return (us)(u >> 16);
}
__device__ __forceinline__ float ldin(const void* p, size_t i, int f) {
    return f ? ((const float*)p)[i] : bf2f(((const us*)p)[i]);
}

__device__ __forceinline__ void gload_lds16(const void* g, void* l) {
    __builtin_amdgcn_global_load_lds(
        (const __attribute__((address_space(1))) void*)g,
        (__attribute__((address_space(3))) void*)l, 16, 0, 0);
}

// ------------------------------------------------------------------
// Dtype probe: bf16 NaN/Inf patterns ((u&0x7F80)==0x7F80) occur w.p. 2^-8
// per halfword in fp32 buffers (uniform low-mantissa halfwords), never in
// genuine bf16 randn data. Round-1 evidence: harness runs fp32 (flag=1).
// ------------------------------------------------------------------
__global__ void detect_dtype(const us* __restrict__ x, int* __restrict__ flag)
{
    __shared__ int cnt;
    if (threadIdx.x == 0) cnt = 0;
    __syncthreads();
    int c = 0;
    for (int i = threadIdx.x; i < 32768; i += 256) {
        us u = x[i];
        if ((u & 0x7F80u) == 0x7F80u) c++;
    }
    atomicAdd(&cnt, c);
    __syncthreads();
    if (threadIdx.x == 0) *flag = (cnt > 0) ? 1 : 0;
}

// ------------------------------------------------------------------
// Split rows into planar hi/lo bf16: out[row][0:K]=hi, out[row][K:2K]=lo.
// Works for fp32 or bf16 input (bf16 -> lo==0). One block per row.
// ------------------------------------------------------------------
__global__ __launch_bounds__(256)
void split_rows(const void* __restrict__ in, us* __restrict__ out,
                const int* __restrict__ flag, int K)
{
    const int f = *flag;
    const size_t row = blockIdx.x;
    for (int c = threadIdx.x; c < K; c += 256) {
        const float v = ldin(in, row * (size_t)K + c, f);
        const us hi = f2bf(v);
        out[row * (size_t)(2 * K) + c] = hi;
        out[row * (size_t)(2 * K) + K + c] = f2bf(v - bf2f(hi));
    }
}

// ------------------------------------------------------------------
// Transpose + split: in[R][C] (fp32 or bf16) -> out[C][2R] hi/lo planes.
// ------------------------------------------------------------------
__global__ __launch_bounds__(256)
void transpose_split(const void* __restrict__ in, us* __restrict__ out,
                     int R, int C, const int* __restrict__ flag)
{
    const int f = *flag;
    __shared__ float tile[32][33];
    const int tc = C >> 5;
    const int br = blockIdx.x / tc, bc = blockIdx.x % tc;
    const int tx = threadIdx.x & 31, ty = threadIdx.x >> 5;
    #pragma unroll
    for (int i = 0; i < 32; i += 8)
        tile[ty + i][tx] = ldin(in, (size_t)(br * 32 + ty + i) * C + bc * 32 + tx, f);
    __syncthreads();
    const size_t ld = 2 * (size_t)R;
    #pragma unroll
    for (int i = 0; i < 32; i += 8) {
        const float v = tile[tx][ty + i];
        const us hi = f2bf(v);
        out[(size_t)(bc * 32 + ty + i) * ld + br * 32 + tx] = hi;
        out[(size_t)(bc * 32 + ty + i) * ld + R + br * 32 + tx] = f2bf(v - bf2f(hi));
    }
}

// ------------------------------------------------------------------
// MFMA GEMM core, split-precision: C128x64 = A @ Bt^T over virtual K' = 3K.
// A: [rows][2K] planar (hi cols 0..K-1, lo K..2K-1); Bt: [cols][2K] same.
// Terms: (Ah,Bh) kt<K; (Ah,Bl) K<=kt<2K; (Al,Bh) 2K<=kt<3K. xl*wl dropped
// (~2^-18 rel). fp32 accumulate -> fp32-equivalent numerics.
// 4 waves (2x2), wave computes 64x32 via 4x2 16x16x32 fragments.
// LDS XOR-swizzle byte^=((row&7)<<4): applied by pre-swizzling the
// global_load_lds SOURCE chunk (LDS dest linear, m104/m173) + same XOR on
// ds_read. A/B fragments use identical per-lane k-order -> permutation
// cancels in the dot product.
// ------------------------------------------------------------------
__device__ __forceinline__ void mfma_gemm_core(
    const us* __restrict__ A, size_t arow0,
    const us* __restrict__ Bt, int K,
    int tile_m, int tile_n, us* Alds, us* Blds, f32x4 (&acc)[4][2])
{
    const int t = threadIdx.x;
    const int w = t >> 6, l = t & 63;
    const int lr = l & 15, lg = l >> 4;
    const int rsub = l >> 3;                    // row-in-instruction 0..7
    const int cs = (l & 7) ^ rsub;              // pre-swizzled source chunk
    const size_t ld = 2 * (size_t)K;
    const size_t arowbase = arow0 + (size_t)tile_m * 128;
    const size_t nbase = (size_t)tile_n * 64;
    const int wm = w >> 1, wn = w & 1;

    #pragma unroll
    for (int m = 0; m < 4; ++m)
        #pragma unroll
        for (int n = 0; n < 2; ++n) {
            const f32x4 z = {0.f, 0.f, 0.f, 0.f};
            acc[m][n] = z;
        }

    for (int kt = 0; kt < 3 * K; kt += 64) {
        int aoff, boff;
        if (kt < K)          { aoff = kt;     boff = kt; }          // hi*hi
        else if (kt < 2 * K) { aoff = kt - K; boff = kt; }          // hi*lo
        else                 { aoff = kt - K; boff = kt - 2 * K; }  // lo*hi
        __syncthreads();                        // prev tile fully consumed
        // stage A: 16KB = 16 wave-instructions, 4 per wave
        #pragma unroll
        for (int j = 0; j < 4; ++j) {
            const int inst = w * 4 + j;
            const int r = inst * 8 + rsub;
            gload_lds16(A + (arowbase + r) * ld + aoff + cs * 8,
                        Alds + inst * 512);
        }
        // stage B: 8KB = 8 wave-instructions, 2 per wave
        #pragma unroll
        for (int j = 0; j < 2; ++j) {
            const int inst = w * 2 + j;
            const int r = inst * 8 + rsub;
            gload_lds16(Bt + (nbase + r) * ld + boff + cs * 8,
                        Blds + inst * 512);
        }
        __syncthreads();                        // drains vmcnt before barrier
        #pragma unroll
        for (int kk = 0; kk < 2; ++kk) {        // two K=32 MFMA steps
            bf16x8 af[4], bfr[2];
            #pragma unroll
            for (int m = 0; m < 4; ++m) {
                const int r = wm * 64 + m * 16 + lr;
                const int chunk = ((kk * 4) + lg) ^ (lr & 7);
                af[m] = *(const bf16x8*)(Alds + r * 64 + chunk * 8);
            }
            #pragma unroll
            for (int n = 0; n < 2; ++n) {
                const int r = wn * 32 + n * 16 + lr;
                const int chunk = ((kk * 4) + lg) ^ (lr & 7);
                bfr[n] = *(const bf16x8*)(Blds + r * 64 + chunk * 8);
            }
            #pragma unroll
            for (int m = 0; m < 4; ++m)
                #pragma unroll
                for (int n = 0; n < 2; ++n)
                    acc[m][n] = __builtin_amdgcn_mfma_f32_16x16x32_bf16(
                        af[m], bfr[n], acc[m][n], 0, 0, 0);
        }
    }
}

// qkv = x @ W_qkv + b ; fp32 out into workspace. Used for BOTH dtypes.
__global__ __launch_bounds__(256)
void mfma_gemm_qkv(const us* __restrict__ x16, const us* __restrict__ Wt,
                   const void* __restrict__ bq, float* __restrict__ qkv,
                   const int* __restrict__ flag, size_t row0, int ntm)
{
    const int f = *flag;
    __shared__ us Alds[128 * 64];
    __shared__ us Blds[64 * 64];
    const int tile_m = blockIdx.x % ntm, tile_n = blockIdx.x / ntm;
    f32x4 acc[4][2];
    mfma_gemm_core(x16, row0, Wt, 768, tile_m, tile_n, Alds, Blds, acc);
    const int t = threadIdx.x, w = t >> 6, l = t & 63;
    const int lr = l & 15, lg = l >> 4;
    const int wm = w >> 1, wn = w & 1;
    #pragma unroll
    for (int n = 0; n < 2; ++n) {
        const int col = tile_n * 64 + wn * 32 + n * 16 + lr;
        const float bz = ldin(bq, col, f);
        #pragma unroll
        for (int m = 0; m < 4; ++m) {
            const int row = tile_m * 128 + wm * 64 + m * 16 + lg * 4;
            float* op = qkv + (size_t)row * 2496 + col;
            #pragma unroll
            for (int r = 0; r < 4; ++r)
                op[(size_t)r * 2496] = acc[m][n][r] + bz;
        }
    }
}

// out = xc @ proj_W + pb ; dtype-aware store. Used for BOTH dtypes.
__global__ __launch_bounds__(256)
void mfma_gemm_proj(const us* __restrict__ xc16, const us* __restrict__ Pt,
                    const void* __restrict__ pb, void* __restrict__ out,
                    const int* __restrict__ flag, size_t row0, int ntm)
{
    const int f = *flag;
    __shared__ us Alds[128 * 64];
    __shared__ us Blds[64 * 64];
    const int tile_m = blockIdx.x % ntm, tile_n = blockIdx.x / ntm;
    f32x4 acc[4][2];
    mfma_gemm_core(xc16, 0, Pt, 832, tile_m, tile_n, Alds, Blds, acc);
    const int t = threadIdx.x, w = t >> 6, l = t & 63;
    const int lr = l & 15, lg = l >> 4;
    const int wm = w >> 1, wn = w & 1;
    #pragma unroll
    for (int n = 0; n < 2; ++n) {
        const int col = tile_n * 64 + wn * 32 + n * 16 + lr;
        const float bz = ldin(pb, col, f);
        #pragma unroll
        for (int m = 0; m < 4; ++m) {
            const int row = tile_m * 128 + wm * 64 + m * 16 + lg * 4;
            #pragma unroll
            for (int r = 0; r < 4; ++r) {
                const float val = acc[m][n][r] + bz;
                if (f) ((float*)out)[(row0 + row + r) * 768 + col] = val;
                else   ((us*)out)[(row0 + row + r) * 768 + col] = f2bf(val);
            }
        }
    }
}

// ------------------------------------------------------------------
// r1,r2 = elementwise(z1,z2,v); thread per (bh, n, e)   (unchanged)
// ------------------------------------------------------------------
__global__ __launch_bounds__(256)
void zr_kernel(const float* __restrict__ qkv, const void* __restrict__ w1,
               const void* __restrict__ w2, float* __restrict__ r1,
               float* __restrict__ r2, const int* __restrict__ flag, int CB)
{
    const int f = *flag;
    const size_t tid = (size_t)blockIdx.x * 256 + threadIdx.x;
    if (tid >= (size_t)CB * 12 * 1024 * 64) return;
    const int e = (int)(tid & 63);
    const size_t rest = tid >> 6;
    const int n = (int)(rest & 1023);
    const int bh = (int)(rest >> 10);
    const int b = bh / 12, h = bh % 12;
    const float* krow = qkv + ((size_t)b * 1024 + n) * 2496 + 768 + h * 64;
    float z1 = 0.f, z2 = 0.f;
    if (f) {
        const float* w1p = (const float*)w1 + (size_t)h * 4096 + e;
        const float* w2p = (const float*)w2 + (size_t)h * 4096 + e;
        for (int d = 0; d < 64; d++) {
            const float kv = krow[d];
            z1 += kv * w1p[d * 64]; z2 += kv * w2p[d * 64];
        }
    } else {
        const us* w1p = (const us*)w1 + (size_t)h * 4096 + e;
        const us* w2p = (const us*)w2 + (size_t)h * 4096 + e;
        for (int d = 0; d < 64; d++) {
            const float kv = krow[d];
            z1 += kv * bf2f(w1p[d * 64]); z2 += kv * bf2f(w2p[d * 64]);
        }
    }
    const float vv = qkv[((size_t)b * 1024 + n) * 2496 + 1536 + h * 64 + e];
    const float ec = vv * (-1.0f / 3072.0f);
    const float sig = 1.f / (1.f + __expf(-z2));
    r1[tid] = ec * z2 * sig;
    r2[tid] = ec * z1 * (sig * (1.f + z2 * (1.f - sig)));
}

// ------------------------------------------------------------------
// grad update (unchanged)
// ------------------------------------------------------------------
__global__ __launch_bounds__(256)
void grad_update(const float* __restrict__ qkv, const float* __restrict__ r1,
                 const float* __restrict__ r2, const void* __restrict__ w1,
                 const void* __restrict__ w2, float* __restrict__ wu1,
                 float* __restrict__ wu2, const int* __restrict__ flag)
{
    const int f = *flag;
    const int bh = blockIdx.x, b = bh / 12, h = bh % 12;
    __shared__ float ks[64][64];
    __shared__ float gs[2][64][65];
    __shared__ float inv[2][64];
    const int t = threadIdx.x;
    const int e = t & 63, dq = t >> 6;
    float g1[16], g2[16];
    for (int i = 0; i < 16; i++) { g1[i] = 0.f; g2[i] = 0.f; }
    for (int ch = 0; ch < 16; ch++) {
        const int n0 = ch * 64;
        __syncthreads();
        for (int i = t; i < 4096; i += 256) {
            const int nn = i >> 6, dd = i & 63;
            ks[nn][dd] = qkv[((size_t)b * 1024 + n0 + nn) * 2496 + 768 + h * 64 + dd];
        }
        __syncthreads();
        const float* r1p = r1 + ((size_t)bh * 1024 + n0) * 64 + e;
        const float* r2p = r2 + ((size_t)bh * 1024 + n0) * 64 + e;
        for (int nn = 0; nn < 64; nn++) {
            const float rv1 = r1p[nn * 64], rv2 = r2p[nn * 64];
            for (int i = 0; i < 16; i++) {
                const float kv = ks[nn][dq + i * 4];
                g1[i] += kv * rv1; g2[i] += kv * rv2;
            }
        }
    }
    __syncthreads();
    for (int i = 0; i < 16; i++) { gs[0][dq + i * 4][e] = g1[i]; gs[1][dq + i * 4][e] = g2[i]; }
    __syncthreads();
    if (t < 128) {
        const int w = t >> 6, ee = t & 63;
        float s = 0.f;
        for (int d = 0; d < 64; d++) { const float g = gs[w][d][ee]; s += g * g; }
        inv[w][ee] = 1.f / (sqrtf(s) + 1.f);
    }
    __syncthreads();
    for (int i = t; i < 4096; i += 256) {
        const int d = i >> 6, ee = i & 63;
        const float w1v = ldin(w1, (size_t)h * 4096 + i, f);
        const float w2v = ldin(w2, (size_t)h * 4096 + i, f);
        wu1[(size_t)bh * 4096 + i] = w1v - gs[0][d][ee] * inv[0][ee];
        wu2[(size_t)bh * 4096 + i] = w2v - gs[1][d][ee] * inv[1][ee];
    }
}

// ------------------------------------------------------------------
// x1 = (q@wu1)*silu(q@wu2); ALWAYS stores hi+lo bf16 planes into xc16
// ------------------------------------------------------------------
__global__ __launch_bounds__(256)
void x1_kernel(const float* __restrict__ qkv, const float* __restrict__ wu1,
               const float* __restrict__ wu2, us* __restrict__ xc16, int CB)
{
    const size_t tid = (size_t)blockIdx.x * 256 + threadIdx.x;
    if (tid >= (size_t)CB * 12 * 1024 * 64) return;
    const int e = (int)(tid & 63);
    const size_t rest = tid >> 6;
    const int n = (int)(rest & 1023);
    const int bh = (int)(rest >> 10);
    const int b = bh / 12, h = bh % 12;
    const float* qrow = qkv + ((size_t)b * 1024 + n) * 2496 + h * 64;
    const float* w1p = wu1 + (size_t)bh * 4096 + e;
    const float* w2p = wu2 + (size_t)bh * 4096 + e;
    float z1 = 0.f, z2 = 0.f;
    for (int d = 0; d < 64; d++) {
        const float qv = qrow[d];
        z1 += qv * w1p[d * 64]; z2 += qv * w2p[d * 64];
    }
    const float sig = 1.f / (1.f + __expf(-z2));
    const float val = z1 * z2 * sig;
    const size_t rb = (size_t)b * 1024 + n;
    const int c = h * 64 + e;
    const us hi = f2bf(val);
    xc16[rb * 1664 + c] = hi;
    xc16[rb * 1664 + 832 + c] = f2bf(val - bf2f(hi));
}

// ------------------------------------------------------------------
// Depthwise 3x3 branch; ALWAYS stores hi+lo bf16 planes into xc16
// ------------------------------------------------------------------
__global__ __launch_bounds__(256)
void dwc_f32(const float* __restrict__ qkv, const void* __restrict__ w3,
             us* __restrict__ xc16, const int* __restrict__ flag)
{
    const int f = *flag;
    __shared__ float qch[4][1026], kch[4][1026], vch[4][1026];
    __shared__ float w3s[4][12];
    const int b = blockIdx.x >> 4, dg = blockIdx.x & 15;
    const int t = threadIdx.x;
    for (int rr = 0; rr < 4; rr++) {
        const int n = t + rr * 256;
        const float* rp = qkv + ((size_t)b * 1024 + n) * 2496 + 2304 + dg * 4;
        for (int c = 0; c < 4; c++) {
            qch[c][n] = rp[c]; kch[c][n] = rp[64 + c]; vch[c][n] = rp[128 + c];
        }
    }
    __syncthreads();
    if (t < 128) {
        const int c = t >> 5, x = t & 31;
        float g[9];
        for (int i = 0; i < 9; i++) g[i] = 0.f;
        for (int y = 0; y < 32; y++) {
            const float e = vch[c][y * 32 + x] * (-1.0f / 3072.0f);
            for (int dy = -1; dy <= 1; dy++) {
                const int yy = y + dy;
                if (yy < 0 || yy > 31) continue;
                for (int dx = -1; dx <= 1; dx++) {
                    const int xx = x + dx;
                    if (xx < 0 || xx > 31) continue;
                    g[(dy + 1) * 3 + dx + 1] += kch[c][yy * 32 + xx] * e;
                }
            }
        }
        for (int m = 16; m >= 1; m >>= 1)
            for (int i = 0; i < 9; i++)
                g[i] += __shfl_xor(g[i], m, 64);
        if (x == 0) {
            float s = 0.f;
            for (int i = 0; i < 9; i++) s += g[i] * g[i];
            const float nrm = 1.f / (sqrtf(s) + 1.f);
            const int d = dg * 4 + c;
            for (int i = 0; i < 9; i++)
                w3s[c][i] = ldin(w3, (size_t)d * 9 + i, f) - g[i] * nrm;
        }
    }
    __syncthreads();
    for (int rr = 0; rr < 4; rr++) {
        const int n = t + rr * 256;
        const int y = n >> 5, xx = n & 31;
        for (int cc = 0; cc < 4; cc++) {
            float acc = 0.f;
            for (int ky = 0; ky < 3; ky++) {
                const int yy = y + ky - 1;
                if (yy < 0 || yy > 31) continue;
                for (int kx = 0; kx < 3; kx++) {
                    const int xz = xx + kx - 1;
                    if (xz < 0 || xz > 31) continue;
                    acc += qch[cc][yy * 32 + xz] * w3s[cc][ky * 3 + kx];
                }
            }
            const size_t rb = (size_t)b * 1024 + n;
            const int c = 768 + dg * 4 + cc;
            const us hi = f2bf(acc);
            xc16[rb * 1664 + c] = hi;
            xc16[rb * 1664 + 832 + c] = f2bf(acc - bf2f(hi));
        }
    }
}

// ------------------------------------------------------------------
// ws layout: [flag 256B][Wt 2496x1536 bf16][Pt 768x1664 bf16]
//            [x16 32768x1536 bf16][CB fp32 region]
// CB unit fp32 elems: qkv 1024*2496 + r1/r2 2*786432 + wu 2*49152
//   + xc16 (1024*1664 us == 1024*832 fp32-equivalent bytes) = 5,079,040
// ------------------------------------------------------------------
extern "C" void kernel_launch(void* const* d_in, const int* in_sizes, int n_in,
                              void* d_out, int out_size, void* d_ws, size_t ws_size,
                              hipStream_t stream) {
    const void* x      = d_in[0];
    const void* W_qkv  = d_in[1];
    const void* b_qkv  = d_in[2];
    const void* w1     = d_in[3];
    const void* w2     = d_in[4];
    const void* w3     = d_in[5];
    const void* proj_W = d_in[6];
    const void* proj_b = d_in[7];

    int* flag = (int*)d_ws;
    char* wsB = (char*)d_ws + 256;
    us* Wt  = (us*)wsB;                                       //  7,667,712 B
    us* Pt  = (us*)(wsB + (size_t)2496 * 1536 * 2);           //  2,555,904 B
    us* x16 = (us*)(wsB + (size_t)2496 * 1536 * 2
                        + (size_t)768 * 1664 * 2);            // 100,663,296 B
    float* base = (float*)((char*)x16 + (size_t)32768 * 1536 * 2);

    const size_t per  = 5079040ULL;  // fp32 elems per CB unit
    const size_t head = 256 + (size_t)2496 * 1536 * 2 + (size_t)768 * 1664 * 2
                            + (size_t)32768 * 1536 * 2;
    int CB = 1;
    for (int cand = 32; cand >= 1; cand >>= 1)
        if (head + per * cand * 4 <= ws_size) { CB = cand; break; }

    float* qkv_c = base;
    float* r1  = qkv_c + (size_t)CB * 1024 * 2496;
    float* r2  = r1  + (size_t)CB * 12 * 1024 * 64;
    float* wu1 = r2  + (size_t)CB * 12 * 1024 * 64;
    float* wu2 = wu1 + (size_t)CB * 12 * 4096;
    us*    xc16 = (us*)(wu2 + (size_t)CB * 12 * 4096);

    detect_dtype<<<1, 256, 0, stream>>>((const us*)x, flag);
    // one-time conversions (dtype-aware via flag; fp32 -> hi/lo split)
    split_rows<<<32768, 256, 0, stream>>>(x, x16, flag, 768);
    transpose_split<<<(768 / 32) * (2496 / 32), 256, 0, stream>>>(
        W_qkv, Wt, 768, 2496, flag);
    transpose_split<<<(832 / 32) * (768 / 32), 256, 0, stream>>>(
        proj_W, Pt, 832, 768, flag);

    const int passes = 32 / CB;
    const int nrows = CB * 1024;
    const int ntm = nrows / 128;
    for (int p = 0; p < passes; p++) {
        const size_t row0 = (size_t)p * CB * 1024;
        mfma_gemm_qkv<<<ntm * 39, 256, 0, stream>>>(
            x16, Wt, b_qkv, qkv_c, flag, row0, ntm);
        zr_kernel<<<CB * 3072, 256, 0, stream>>>(qkv_c, w1, w2, r1, r2, flag, CB);
        grad_update<<<CB * 12, 256, 0, stream>>>(qkv_c, r1, r2, w1, w2, wu1, wu2, flag);
        x1_kernel<<<CB * 3072, 256, 0, stream>>>(qkv_c, wu1, wu2, xc16, CB);
        dwc_f32<<<CB * 16, 256, 0, stream>>>(qkv_c, w3, xc16, flag);
        mfma_gemm_proj<<<ntm * 12, 256, 0, stream>>>(
            xc16, Pt, proj_b, d_out, flag, row0, ntm);
    }
}

// Round 5
// 2266.383 us; speedup vs baseline: 9.9892x; 1.2639x over previous
//
#include <hip/hip_runtime.h>
#include <stdint.h>

typedef unsigned short us;
using bf16x8 = __attribute__((ext_vector_type(8))) __bf16;
using f32x4  = __attribute__((ext_vector_type(4))) float;

__device__ __forceinline__ float bf2f(us x) {
    union { unsigned u; float f; } v; v.u = ((unsigned)x) << 16; return v.f;
}
__device__ __forceinline__ us f2bf(float f) {
    union { float f; unsigned u; } v; v.f = f;
    unsigned u = v.u;
    u += 0x7FFFu + ((u >> 16) & 1u);   // RNE
    return (us)(u >> 16);
}
__device__ __forceinline__ float ldin(const void* p, size_t i, int f) {
    return f ? ((const float*)p)[i] : bf2f(((const us*)p)[i]);
}

__device__ __forceinline__ void gload_lds16(const void* g, void* l) {
    __builtin_amdgcn_global_load_lds(
        (const __attribute__((address_space(1))) void*)g,
        (__attribute__((address_space(3))) void*)l, 16, 0, 0);
}

// ------------------------------------------------------------------
// Dtype probe: bf16 NaN/Inf patterns ((u&0x7F80)==0x7F80) occur w.p. 2^-8
// per halfword in fp32 buffers, never in genuine bf16 randn data.
// Measured: harness runs fp32 (flag=1).
// ------------------------------------------------------------------
__global__ void detect_dtype(const us* __restrict__ x, int* __restrict__ flag)
{
    __shared__ int cnt;
    if (threadIdx.x == 0) cnt = 0;
    __syncthreads();
    int c = 0;
    for (int i = threadIdx.x; i < 32768; i += 256) {
        us u = x[i];
        if ((u & 0x7F80u) == 0x7F80u) c++;
    }
    atomicAdd(&cnt, c);
    __syncthreads();
    if (threadIdx.x == 0) *flag = (cnt > 0) ? 1 : 0;
}

// ------------------------------------------------------------------
// Split rows into planar hi/lo bf16: out[row][0:K]=hi, out[row][K:2K]=lo.
// ------------------------------------------------------------------
__global__ __launch_bounds__(256)
void split_rows(const void* __restrict__ in, us* __restrict__ out,
                const int* __restrict__ flag, int K)
{
    const int f = *flag;
    const size_t row = blockIdx.x;
    for (int c = threadIdx.x; c < K; c += 256) {
        const float v = ldin(in, row * (size_t)K + c, f);
        const us hi = f2bf(v);
        out[row * (size_t)(2 * K) + c] = hi;
        out[row * (size_t)(2 * K) + K + c] = f2bf(v - bf2f(hi));
    }
}

// ------------------------------------------------------------------
// Transpose + split: in[R][C] (fp32 or bf16) -> out[C][2R] hi/lo planes.
// ------------------------------------------------------------------
__global__ __launch_bounds__(256)
void transpose_split(const void* __restrict__ in, us* __restrict__ out,
                     int R, int C, const int* __restrict__ flag)
{
    const int f = *flag;
    __shared__ float tile[32][33];
    const int tc = C >> 5;
    const int br = blockIdx.x / tc, bc = blockIdx.x % tc;
    const int tx = threadIdx.x & 31, ty = threadIdx.x >> 5;
    #pragma unroll
    for (int i = 0; i < 32; i += 8)
        tile[ty + i][tx] = ldin(in, (size_t)(br * 32 + ty + i) * C + bc * 32 + tx, f);
    __syncthreads();
    const size_t ld = 2 * (size_t)R;
    #pragma unroll
    for (int i = 0; i < 32; i += 8) {
        const float v = tile[tx][ty + i];
        const us hi = f2bf(v);
        out[(size_t)(bc * 32 + ty + i) * ld + br * 32 + tx] = hi;
        out[(size_t)(bc * 32 + ty + i) * ld + R + br * 32 + tx] = f2bf(v - bf2f(hi));
    }
}

// ------------------------------------------------------------------
// MFMA GEMM core, split-precision (verified R2: 7.9x, absmax unchanged).
// C128x64 = A @ Bt^T over virtual K' = 3K; xl*wl dropped (~2^-18 rel).
// ------------------------------------------------------------------
__device__ __forceinline__ void mfma_gemm_core(
    const us* __restrict__ A, size_t arow0,
    const us* __restrict__ Bt, int K,
    int tile_m, int tile_n, us* Alds, us* Blds, f32x4 (&acc)[4][2])
{
    const int t = threadIdx.x;
    const int w = t >> 6, l = t & 63;
    const int lr = l & 15, lg = l >> 4;
    const int rsub = l >> 3;                    // row-in-instruction 0..7
    const int cs = (l & 7) ^ rsub;              // pre-swizzled source chunk
    const size_t ld = 2 * (size_t)K;
    const size_t arowbase = arow0 + (size_t)tile_m * 128;
    const size_t nbase = (size_t)tile_n * 64;
    const int wm = w >> 1, wn = w & 1;

    #pragma unroll
    for (int m = 0; m < 4; ++m)
        #pragma unroll
        for (int n = 0; n < 2; ++n) {
            const f32x4 z = {0.f, 0.f, 0.f, 0.f};
            acc[m][n] = z;
        }

    for (int kt = 0; kt < 3 * K; kt += 64) {
        int aoff, boff;
        if (kt < K)          { aoff = kt;     boff = kt; }          // hi*hi
        else if (kt < 2 * K) { aoff = kt - K; boff = kt; }          // hi*lo
        else                 { aoff = kt - K; boff = kt - 2 * K; }  // lo*hi
        __syncthreads();
        #pragma unroll
        for (int j = 0; j < 4; ++j) {
            const int inst = w * 4 + j;
            const int r = inst * 8 + rsub;
            gload_lds16(A + (arowbase + r) * ld + aoff + cs * 8,
                        Alds + inst * 512);
        }
        #pragma unroll
        for (int j = 0; j < 2; ++j) {
            const int inst = w * 2 + j;
            const int r = inst * 8 + rsub;
            gload_lds16(Bt + (nbase + r) * ld + boff + cs * 8,
                        Blds + inst * 512);
        }
        __syncthreads();
        #pragma unroll
        for (int kk = 0; kk < 2; ++kk) {
            bf16x8 af[4], bfr[2];
            #pragma unroll
            for (int m = 0; m < 4; ++m) {
                const int r = wm * 64 + m * 16 + lr;
                const int chunk = ((kk * 4) + lg) ^ (lr & 7);
                af[m] = *(const bf16x8*)(Alds + r * 64 + chunk * 8);
            }
            #pragma unroll
            for (int n = 0; n < 2; ++n) {
                const int r = wn * 32 + n * 16 + lr;
                const int chunk = ((kk * 4) + lg) ^ (lr & 7);
                bfr[n] = *(const bf16x8*)(Blds + r * 64 + chunk * 8);
            }
            #pragma unroll
            for (int m = 0; m < 4; ++m)
                #pragma unroll
                for (int n = 0; n < 2; ++n)
                    acc[m][n] = __builtin_amdgcn_mfma_f32_16x16x32_bf16(
                        af[m], bfr[n], acc[m][n], 0, 0, 0);
        }
    }
}

// qkv = x @ W_qkv + b ; fp32 out into workspace.
__global__ __launch_bounds__(256)
void mfma_gemm_qkv(const us* __restrict__ x16, const us* __restrict__ Wt,
                   const void* __restrict__ bq, float* __restrict__ qkv,
                   const int* __restrict__ flag, size_t row0, int ntm)
{
    const int f = *flag;
    __shared__ us Alds[128 * 64];
    __shared__ us Blds[64 * 64];
    const int tile_m = blockIdx.x % ntm, tile_n = blockIdx.x / ntm;
    f32x4 acc[4][2];
    mfma_gemm_core(x16, row0, Wt, 768, tile_m, tile_n, Alds, Blds, acc);
    const int t = threadIdx.x, w = t >> 6, l = t & 63;
    const int lr = l & 15, lg = l >> 4;
    const int wm = w >> 1, wn = w & 1;
    #pragma unroll
    for (int n = 0; n < 2; ++n) {
        const int col = tile_n * 64 + wn * 32 + n * 16 + lr;
        const float bz = ldin(bq, col, f);
        #pragma unroll
        for (int m = 0; m < 4; ++m) {
            const int row = tile_m * 128 + wm * 64 + m * 16 + lg * 4;
            float* op = qkv + (size_t)row * 2496 + col;
            #pragma unroll
            for (int r = 0; r < 4; ++r)
                op[(size_t)r * 2496] = acc[m][n][r] + bz;
        }
    }
}

// out = xc @ proj_W + pb ; dtype-aware store.
__global__ __launch_bounds__(256)
void mfma_gemm_proj(const us* __restrict__ xc16, const us* __restrict__ Pt,
                    const void* __restrict__ pb, void* __restrict__ out,
                    const int* __restrict__ flag, size_t row0, int ntm)
{
    const int f = *flag;
    __shared__ us Alds[128 * 64];
    __shared__ us Blds[64 * 64];
    const int tile_m = blockIdx.x % ntm, tile_n = blockIdx.x / ntm;
    f32x4 acc[4][2];
    mfma_gemm_core(xc16, 0, Pt, 832, tile_m, tile_n, Alds, Blds, acc);
    const int t = threadIdx.x, w = t >> 6, l = t & 63;
    const int lr = l & 15, lg = l >> 4;
    const int wm = w >> 1, wn = w & 1;
    #pragma unroll
    for (int n = 0; n < 2; ++n) {
        const int col = tile_n * 64 + wn * 32 + n * 16 + lr;
        const float bz = ldin(pb, col, f);
        #pragma unroll
        for (int m = 0; m < 4; ++m) {
            const int row = tile_m * 128 + wm * 64 + m * 16 + lg * 4;
            #pragma unroll
            for (int r = 0; r < 4; ++r) {
                const float val = acc[m][n][r] + bz;
                if (f) ((float*)out)[(row0 + row + r) * 768 + col] = val;
                else   ((us*)out)[(row0 + row + r) * 768 + col] = f2bf(val);
            }
        }
    }
}

// ------------------------------------------------------------------
// r1,r2 = elementwise(z1,z2,v); thread per (bh, n, e)
// ------------------------------------------------------------------
__global__ __launch_bounds__(256)
void zr_kernel(const float* __restrict__ qkv, const void* __restrict__ w1,
               const void* __restrict__ w2, float* __restrict__ r1,
               float* __restrict__ r2, const int* __restrict__ flag, int CB)
{
    const int f = *flag;
    const size_t tid = (size_t)blockIdx.x * 256 + threadIdx.x;
    if (tid >= (size_t)CB * 12 * 1024 * 64) return;
    const int e = (int)(tid & 63);
    const size_t rest = tid >> 6;
    const int n = (int)(rest & 1023);
    const int bh = (int)(rest >> 10);
    const int b = bh / 12, h = bh % 12;
    const float* krow = qkv + ((size_t)b * 1024 + n) * 2496 + 768 + h * 64;
    float z1 = 0.f, z2 = 0.f;
    if (f) {
        const float* w1p = (const float*)w1 + (size_t)h * 4096 + e;
        const float* w2p = (const float*)w2 + (size_t)h * 4096 + e;
        for (int d = 0; d < 64; d++) {
            const float kv = krow[d];
            z1 += kv * w1p[d * 64]; z2 += kv * w2p[d * 64];
        }
    } else {
        const us* w1p = (const us*)w1 + (size_t)h * 4096 + e;
        const us* w2p = (const us*)w2 + (size_t)h * 4096 + e;
        for (int d = 0; d < 64; d++) {
            const float kv = krow[d];
            z1 += kv * bf2f(w1p[d * 64]); z2 += kv * bf2f(w2p[d * 64]);
        }
    }
    const float vv = qkv[((size_t)b * 1024 + n) * 2496 + 1536 + h * 64 + e];
    const float ec = vv * (-1.0f / 3072.0f);
    const float sig = 1.f / (1.f + __expf(-z2));
    r1[tid] = ec * z2 * sig;
    r2[tid] = ec * z1 * (sig * (1.f + z2 * (1.f - sig)));
}

// ------------------------------------------------------------------
// grad stage 1: partial g over a 128-row n-slice. block = (bh, slice s of 8).
// Deterministic partials to gpart (no atomics). 8x block count vs old
// grad_update (which ran at 4.3% occupancy, 223 us).
// ------------------------------------------------------------------
__global__ __launch_bounds__(256)
void grad_partial(const float* __restrict__ qkv, const float* __restrict__ r1,
                  const float* __restrict__ r2, float* __restrict__ gpart)
{
    const int s = blockIdx.x & 7;
    const int bh = blockIdx.x >> 3;
    const int b = bh / 12, h = bh % 12;
    __shared__ float ks[64][64];
    const int t = threadIdx.x;
    const int e = t & 63, dq = t >> 6;
    float g1[16], g2[16];
    for (int i = 0; i < 16; i++) { g1[i] = 0.f; g2[i] = 0.f; }
    for (int ch = 0; ch < 2; ch++) {
        const int n0 = s * 128 + ch * 64;
        __syncthreads();
        for (int i = t; i < 4096; i += 256) {
            const int nn = i >> 6, dd = i & 63;
            ks[nn][dd] = qkv[((size_t)b * 1024 + n0 + nn) * 2496 + 768 + h * 64 + dd];
        }
        __syncthreads();
        const float* r1p = r1 + ((size_t)bh * 1024 + n0) * 64 + e;
        const float* r2p = r2 + ((size_t)bh * 1024 + n0) * 64 + e;
        for (int nn = 0; nn < 64; nn++) {
            const float rv1 = r1p[nn * 64], rv2 = r2p[nn * 64];
            for (int i = 0; i < 16; i++) {
                const float kv = ks[nn][dq + i * 4];
                g1[i] += kv * rv1; g2[i] += kv * rv2;
            }
        }
    }
    float* gp = gpart + (size_t)blockIdx.x * 8192;
    for (int i = 0; i < 16; i++) {
        gp[(dq + i * 4) * 64 + e] = g1[i];
        gp[4096 + (dq + i * 4) * 64 + e] = g2[i];
    }
}

// ------------------------------------------------------------------
// grad stage 2: sum 8 slices, per-e norm over d, wu = w - g*inv.
// ------------------------------------------------------------------
__global__ __launch_bounds__(256)
void grad_finalize(const float* __restrict__ gpart, const void* __restrict__ w1,
                   const void* __restrict__ w2, float* __restrict__ wu1,
                   float* __restrict__ wu2, const int* __restrict__ flag)
{
    const int f = *flag;
    const int bh = blockIdx.x, h = bh % 12;
    __shared__ float gs[2][64][65];
    __shared__ float inv[2][64];
    const int t = threadIdx.x;
    for (int i = t; i < 4096; i += 256) {
        float a0 = 0.f, a1 = 0.f;
        const float* gp = gpart + (size_t)bh * 8 * 8192;
        for (int s = 0; s < 8; s++) {
            a0 += gp[(size_t)s * 8192 + i];
            a1 += gp[(size_t)s * 8192 + 4096 + i];
        }
        gs[0][i >> 6][i & 63] = a0;
        gs[1][i >> 6][i & 63] = a1;
    }
    __syncthreads();
    if (t < 128) {
        const int w = t >> 6, ee = t & 63;
        float sacc = 0.f;
        for (int d = 0; d < 64; d++) { const float g = gs[w][d][ee]; sacc += g * g; }
        inv[w][ee] = 1.f / (sqrtf(sacc) + 1.f);
    }
    __syncthreads();
    for (int i = t; i < 4096; i += 256) {
        const int d = i >> 6, ee = i & 63;
        const float w1v = ldin(w1, (size_t)h * 4096 + i, f);
        const float w2v = ldin(w2, (size_t)h * 4096 + i, f);
        wu1[(size_t)bh * 4096 + i] = w1v - gs[0][d][ee] * inv[0][ee];
        wu2[(size_t)bh * 4096 + i] = w2v - gs[1][d][ee] * inv[1][ee];
    }
}

// ------------------------------------------------------------------
// x1 = (q@wu1)*silu(q@wu2); stores hi+lo bf16 planes into xc16
// ------------------------------------------------------------------
__global__ __launch_bounds__(256)
void x1_kernel(const float* __restrict__ qkv, const float* __restrict__ wu1,
               const float* __restrict__ wu2, us* __restrict__ xc16, int CB)
{
    const size_t tid = (size_t)blockIdx.x * 256 + threadIdx.x;
    if (tid >= (size_t)CB * 12 * 1024 * 64) return;
    const int e = (int)(tid & 63);
    const size_t rest = tid >> 6;
    const int n = (int)(rest & 1023);
    const int bh = (int)(rest >> 10);
    const int b = bh / 12, h = bh % 12;
    const float* qrow = qkv + ((size_t)b * 1024 + n) * 2496 + h * 64;
    const float* w1p = wu1 + (size_t)bh * 4096 + e;
    const float* w2p = wu2 + (size_t)bh * 4096 + e;
    float z1 = 0.f, z2 = 0.f;
    for (int d = 0; d < 64; d++) {
        const float qv = qrow[d];
        z1 += qv * w1p[d * 64]; z2 += qv * w2p[d * 64];
    }
    const float sig = 1.f / (1.f + __expf(-z2));
    const float val = z1 * z2 * sig;
    const size_t rb = (size_t)b * 1024 + n;
    const int c = h * 64 + e;
    const us hi = f2bf(val);
    xc16[rb * 1664 + c] = hi;
    xc16[rb * 1664 + 832 + c] = f2bf(val - bf2f(hi));
}

// ------------------------------------------------------------------
// Depthwise 3x3 branch. Gradient phase uses all 256 threads:
// one wave per channel (c = t>>6), lane covers (ys,x), 16 y-rows each,
// full 64-lane shuffle reduce.
// ------------------------------------------------------------------
__global__ __launch_bounds__(256)
void dwc_f32(const float* __restrict__ qkv, const void* __restrict__ w3,
             us* __restrict__ xc16, const int* __restrict__ flag)
{
    const int f = *flag;
    __shared__ float qch[4][1026], kch[4][1026], vch[4][1026];
    __shared__ float w3s[4][12];
    const int b = blockIdx.x >> 4, dg = blockIdx.x & 15;
    const int t = threadIdx.x;
    for (int rr = 0; rr < 4; rr++) {
        const int n = t + rr * 256;
        const float* rp = qkv + ((size_t)b * 1024 + n) * 2496 + 2304 + dg * 4;
        for (int c = 0; c < 4; c++) {
            qch[c][n] = rp[c]; kch[c][n] = rp[64 + c]; vch[c][n] = rp[128 + c];
        }
    }
    __syncthreads();
    {
        const int c = t >> 6, l = t & 63;
        const int ysb = l >> 5, x = l & 31;
        float g[9];
        for (int i = 0; i < 9; i++) g[i] = 0.f;
        for (int y = ysb * 16; y < ysb * 16 + 16; y++) {
            const float e = vch[c][y * 32 + x] * (-1.0f / 3072.0f);
            for (int dy = -1; dy <= 1; dy++) {
                const int yy = y + dy;
                if (yy < 0 || yy > 31) continue;
                for (int dx = -1; dx <= 1; dx++) {
                    const int xx = x + dx;
                    if (xx < 0 || xx > 31) continue;
                    g[(dy + 1) * 3 + dx + 1] += kch[c][yy * 32 + xx] * e;
                }
            }
        }
        for (int m = 32; m >= 1; m >>= 1)
            for (int i = 0; i < 9; i++)
                g[i] += __shfl_xor(g[i], m, 64);
        if (l == 0) {
            float s = 0.f;
            for (int i = 0; i < 9; i++) s += g[i] * g[i];
            const float nrm = 1.f / (sqrtf(s) + 1.f);
            const int d = dg * 4 + c;
            for (int i = 0; i < 9; i++)
                w3s[c][i] = ldin(w3, (size_t)d * 9 + i, f) - g[i] * nrm;
        }
    }
    __syncthreads();
    for (int rr = 0; rr < 4; rr++) {
        const int n = t + rr * 256;
        const int y = n >> 5, xx = n & 31;
        for (int cc = 0; cc < 4; cc++) {
            float acc = 0.f;
            for (int ky = 0; ky < 3; ky++) {
                const int yy = y + ky - 1;
                if (yy < 0 || yy > 31) continue;
                for (int kx = 0; kx < 3; kx++) {
                    const int xz = xx + kx - 1;
                    if (xz < 0 || xz > 31) continue;
                    acc += qch[cc][yy * 32 + xz] * w3s[cc][ky * 3 + kx];
                }
            }
            const size_t rb = (size_t)b * 1024 + n;
            const int c = 768 + dg * 4 + cc;
            const us hi = f2bf(acc);
            xc16[rb * 1664 + c] = hi;
            xc16[rb * 1664 + 832 + c] = f2bf(acc - bf2f(hi));
        }
    }
}

// ------------------------------------------------------------------
// ws layout: [flag 256B][Wt 2496x1536 bf16][Pt 768x1664 bf16]
//            [x16 32768x1536 bf16][CB fp32 region]
// CB unit fp32 elems: qkv 2555904 + r1/r2 2*786432 + gpart 786432
//   + wu 2*49152 + xc 851968 = 5,865,472
// ------------------------------------------------------------------
extern "C" void kernel_launch(void* const* d_in, const int* in_sizes, int n_in,
                              void* d_out, int out_size, void* d_ws, size_t ws_size,
                              hipStream_t stream) {
    const void* x      = d_in[0];
    const void* W_qkv  = d_in[1];
    const void* b_qkv  = d_in[2];
    const void* w1     = d_in[3];
    const void* w2     = d_in[4];
    const void* w3     = d_in[5];
    const void* proj_W = d_in[6];
    const void* proj_b = d_in[7];

    int* flag = (int*)d_ws;
    char* wsB = (char*)d_ws + 256;
    us* Wt  = (us*)wsB;
    us* Pt  = (us*)(wsB + (size_t)2496 * 1536 * 2);
    us* x16 = (us*)(wsB + (size_t)2496 * 1536 * 2 + (size_t)768 * 1664 * 2);
    float* base = (float*)((char*)x16 + (size_t)32768 * 1536 * 2);

    const size_t per  = 5865472ULL;  // fp32 elems per CB unit
    const size_t head = 256 + (size_t)2496 * 1536 * 2 + (size_t)768 * 1664 * 2
                            + (size_t)32768 * 1536 * 2;
    int CB = 1;
    for (int cand = 32; cand >= 1; cand >>= 1)
        if (head + per * cand * 4 <= ws_size) { CB = cand; break; }

    float* qkv_c = base;
    float* r1    = qkv_c + (size_t)CB * 1024 * 2496;
    float* r2    = r1    + (size_t)CB * 786432;
    float* gpart = r2    + (size_t)CB * 786432;
    float* wu1   = gpart + (size_t)CB * 786432;
    float* wu2   = wu1   + (size_t)CB * 49152;
    us*    xc16  = (us*)(wu2 + (size_t)CB * 49152);

    detect_dtype<<<1, 256, 0, stream>>>((const us*)x, flag);
    split_rows<<<32768, 256, 0, stream>>>(x, x16, flag, 768);
    transpose_split<<<(768 / 32) * (2496 / 32), 256, 0, stream>>>(
        W_qkv, Wt, 768, 2496, flag);
    transpose_split<<<(832 / 32) * (768 / 32), 256, 0, stream>>>(
        proj_W, Pt, 832, 768, flag);

    const int passes = 32 / CB;
    const int nrows = CB * 1024;
    const int ntm = nrows / 128;
    for (int p = 0; p < passes; p++) {
        const size_t row0 = (size_t)p * CB * 1024;
        mfma_gemm_qkv<<<ntm * 39, 256, 0, stream>>>(
            x16, Wt, b_qkv, qkv_c, flag, row0, ntm);
        zr_kernel<<<CB * 3072, 256, 0, stream>>>(qkv_c, w1, w2, r1, r2, flag, CB);
        grad_partial<<<CB * 96, 256, 0, stream>>>(qkv_c, r1, r2, gpart);
        grad_finalize<<<CB * 12, 256, 0, stream>>>(gpart, w1, w2, wu1, wu2, flag);
        x1_kernel<<<CB * 3072, 256, 0, stream>>>(qkv_c, wu1, wu2, xc16, CB);
        dwc_f32<<<CB * 16, 256, 0, stream>>>(qkv_c, w3, xc16, flag);
        mfma_gemm_proj<<<ntm * 12, 256, 0, stream>>>(
            xc16, Pt, proj_b, d_out, flag, row0, ntm);
    }
}

// Round 6
// 1592.083 us; speedup vs baseline: 14.2200x; 1.4235x over previous
//
#include <hip/hip_runtime.h>
#include <stdint.h>

typedef unsigned short us;
using bf16x8 = __attribute__((ext_vector_type(8))) __bf16;
using f32x4  = __attribute__((ext_vector_type(4))) float;

__device__ __forceinline__ float bf2f(us x) {
    union { unsigned u; float f; } v; v.u = ((unsigned)x) << 16; return v.f;
}
__device__ __forceinline__ us f2bf(float f) {
    union { float f; unsigned u; } v; v.f = f;
    unsigned u = v.u;
    u += 0x7FFFu + ((u >> 16) & 1u);   // RNE
    return (us)(u >> 16);
}
__device__ __forceinline__ float ldin(const void* p, size_t i, int f) {
    return f ? ((const float*)p)[i] : bf2f(((const us*)p)[i]);
}

__device__ __forceinline__ void gload_lds16(const void* g, void* l) {
    __builtin_amdgcn_global_load_lds(
        (const __attribute__((address_space(1))) void*)g,
        (__attribute__((address_space(3))) void*)l, 16, 0, 0);
}

// ------------------------------------------------------------------
// Dtype probe: bf16 NaN/Inf patterns ((u&0x7F80)==0x7F80) occur w.p. 2^-8
// per halfword in fp32 buffers, never in genuine bf16 randn data.
// Measured: harness runs fp32 (flag=1).
// ------------------------------------------------------------------
__global__ void detect_dtype(const us* __restrict__ x, int* __restrict__ flag)
{
    __shared__ int cnt;
    if (threadIdx.x == 0) cnt = 0;
    __syncthreads();
    int c = 0;
    for (int i = threadIdx.x; i < 32768; i += 256) {
        us u = x[i];
        if ((u & 0x7F80u) == 0x7F80u) c++;
    }
    atomicAdd(&cnt, c);
    __syncthreads();
    if (threadIdx.x == 0) *flag = (cnt > 0) ? 1 : 0;
}

// ------------------------------------------------------------------
// Split rows into planar hi/lo bf16: out[row][0:K]=hi, out[row][K:2K]=lo.
// ------------------------------------------------------------------
__global__ __launch_bounds__(256)
void split_rows(const void* __restrict__ in, us* __restrict__ out,
                const int* __restrict__ flag, int K)
{
    const int f = *flag;
    const size_t row = blockIdx.x;
    for (int c = threadIdx.x; c < K; c += 256) {
        const float v = ldin(in, row * (size_t)K + c, f);
        const us hi = f2bf(v);
        out[row * (size_t)(2 * K) + c] = hi;
        out[row * (size_t)(2 * K) + K + c] = f2bf(v - bf2f(hi));
    }
}

// ------------------------------------------------------------------
// Transpose + split: in[R][C] (fp32 or bf16) -> out[C][2R] hi/lo planes.
// ------------------------------------------------------------------
__global__ __launch_bounds__(256)
void transpose_split(const void* __restrict__ in, us* __restrict__ out,
                     int R, int C, const int* __restrict__ flag)
{
    const int f = *flag;
    __shared__ float tile[32][33];
    const int tc = C >> 5;
    const int br = blockIdx.x / tc, bc = blockIdx.x % tc;
    const int tx = threadIdx.x & 31, ty = threadIdx.x >> 5;
    #pragma unroll
    for (int i = 0; i < 32; i += 8)
        tile[ty + i][tx] = ldin(in, (size_t)(br * 32 + ty + i) * C + bc * 32 + tx, f);
    __syncthreads();
    const size_t ld = 2 * (size_t)R;
    #pragma unroll
    for (int i = 0; i < 32; i += 8) {
        const float v = tile[tx][ty + i];
        const us hi = f2bf(v);
        out[(size_t)(bc * 32 + ty + i) * ld + br * 32 + tx] = hi;
        out[(size_t)(bc * 32 + ty + i) * ld + R + br * 32 + tx] = f2bf(v - bf2f(hi));
    }
}

// ------------------------------------------------------------------
// MFMA GEMM core, split-precision (verified R2: 7.9x, absmax unchanged).
// C128x64 = A @ Bt^T over virtual K' = 3K; xl*wl dropped (~2^-18 rel).
// ------------------------------------------------------------------
__device__ __forceinline__ void mfma_gemm_core(
    const us* __restrict__ A, size_t arow0,
    const us* __restrict__ Bt, int K,
    int tile_m, int tile_n, us* Alds, us* Blds, f32x4 (&acc)[4][2])
{
    const int t = threadIdx.x;
    const int w = t >> 6, l = t & 63;
    const int lr = l & 15, lg = l >> 4;
    const int rsub = l >> 3;                    // row-in-instruction 0..7
    const int cs = (l & 7) ^ rsub;              // pre-swizzled source chunk
    const size_t ld = 2 * (size_t)K;
    const size_t arowbase = arow0 + (size_t)tile_m * 128;
    const size_t nbase = (size_t)tile_n * 64;
    const int wm = w >> 1, wn = w & 1;

    #pragma unroll
    for (int m = 0; m < 4; ++m)
        #pragma unroll
        for (int n = 0; n < 2; ++n) {
            const f32x4 z = {0.f, 0.f, 0.f, 0.f};
            acc[m][n] = z;
        }

    for (int kt = 0; kt < 3 * K; kt += 64) {
        int aoff, boff;
        if (kt < K)          { aoff = kt;     boff = kt; }          // hi*hi
        else if (kt < 2 * K) { aoff = kt - K; boff = kt; }          // hi*lo
        else                 { aoff = kt - K; boff = kt - 2 * K; }  // lo*hi
        __syncthreads();
        #pragma unroll
        for (int j = 0; j < 4; ++j) {
            const int inst = w * 4 + j;
            const int r = inst * 8 + rsub;
            gload_lds16(A + (arowbase + r) * ld + aoff + cs * 8,
                        Alds + inst * 512);
        }
        #pragma unroll
        for (int j = 0; j < 2; ++j) {
            const int inst = w * 2 + j;
            const int r = inst * 8 + rsub;
            gload_lds16(Bt + (nbase + r) * ld + boff + cs * 8,
                        Blds + inst * 512);
        }
        __syncthreads();
        #pragma unroll
        for (int kk = 0; kk < 2; ++kk) {
            bf16x8 af[4], bfr[2];
            #pragma unroll
            for (int m = 0; m < 4; ++m) {
                const int r = wm * 64 + m * 16 + lr;
                const int chunk = ((kk * 4) + lg) ^ (lr & 7);
                af[m] = *(const bf16x8*)(Alds + r * 64 + chunk * 8);
            }
            #pragma unroll
            for (int n = 0; n < 2; ++n) {
                const int r = wn * 32 + n * 16 + lr;
                const int chunk = ((kk * 4) + lg) ^ (lr & 7);
                bfr[n] = *(const bf16x8*)(Blds + r * 64 + chunk * 8);
            }
            #pragma unroll
            for (int m = 0; m < 4; ++m)
                #pragma unroll
                for (int n = 0; n < 2; ++n)
                    acc[m][n] = __builtin_amdgcn_mfma_f32_16x16x32_bf16(
                        af[m], bfr[n], acc[m][n], 0, 0, 0);
        }
    }
}

// qkv = x @ W_qkv + b ; fp32 out into workspace.
__global__ __launch_bounds__(256)
void mfma_gemm_qkv(const us* __restrict__ x16, const us* __restrict__ Wt,
                   const void* __restrict__ bq, float* __restrict__ qkv,
                   const int* __restrict__ flag, size_t row0, int ntm)
{
    const int f = *flag;
    __shared__ us Alds[128 * 64];
    __shared__ us Blds[64 * 64];
    const int tile_m = blockIdx.x % ntm, tile_n = blockIdx.x / ntm;
    f32x4 acc[4][2];
    mfma_gemm_core(x16, row0, Wt, 768, tile_m, tile_n, Alds, Blds, acc);
    const int t = threadIdx.x, w = t >> 6, l = t & 63;
    const int lr = l & 15, lg = l >> 4;
    const int wm = w >> 1, wn = w & 1;
    #pragma unroll
    for (int n = 0; n < 2; ++n) {
        const int col = tile_n * 64 + wn * 32 + n * 16 + lr;
        const float bz = ldin(bq, col, f);
        #pragma unroll
        for (int m = 0; m < 4; ++m) {
            const int row = tile_m * 128 + wm * 64 + m * 16 + lg * 4;
            float* op = qkv + (size_t)row * 2496 + col;
            #pragma unroll
            for (int r = 0; r < 4; ++r)
                op[(size_t)r * 2496] = acc[m][n][r] + bz;
        }
    }
}

// out = xc @ proj_W + pb ; dtype-aware store.
__global__ __launch_bounds__(256)
void mfma_gemm_proj(const us* __restrict__ xc16, const us* __restrict__ Pt,
                    const void* __restrict__ pb, void* __restrict__ out,
                    const int* __restrict__ flag, size_t row0, int ntm)
{
    const int f = *flag;
    __shared__ us Alds[128 * 64];
    __shared__ us Blds[64 * 64];
    const int tile_m = blockIdx.x % ntm, tile_n = blockIdx.x / ntm;
    f32x4 acc[4][2];
    mfma_gemm_core(xc16, 0, Pt, 832, tile_m, tile_n, Alds, Blds, acc);
    const int t = threadIdx.x, w = t >> 6, l = t & 63;
    const int lr = l & 15, lg = l >> 4;
    const int wm = w >> 1, wn = w & 1;
    #pragma unroll
    for (int n = 0; n < 2; ++n) {
        const int col = tile_n * 64 + wn * 32 + n * 16 + lr;
        const float bz = ldin(pb, col, f);
        #pragma unroll
        for (int m = 0; m < 4; ++m) {
            const int row = tile_m * 128 + wm * 64 + m * 16 + lg * 4;
            #pragma unroll
            for (int r = 0; r < 4; ++r) {
                const float val = acc[m][n][r] + bz;
                if (f) ((float*)out)[(row0 + row + r) * 768 + col] = val;
                else   ((us*)out)[(row0 + row + r) * 768 + col] = f2bf(val);
            }
        }
    }
}

// ------------------------------------------------------------------
// zr2: LDS-tiled z1,z2 + elementwise -> r1,r2.
// Block = (bh, 64-row n-chunk); w1[h],w2[h] staged once per block
// ([d][e], +1 pad, conflict-free); k chunk in LDS (uniform-address
// broadcast reads, free). Thread = (e, 16 rows). d-order preserved
// -> bit-identical z vs R5 zr_kernel. Replaces the latency-bound
// thread-per-(n,e) version (152 us, VALUBusy 19%, HBM 6%).
// ------------------------------------------------------------------
__global__ __launch_bounds__(256)
void zr2_kernel(const float* __restrict__ qkv, const void* __restrict__ w1,
                const void* __restrict__ w2, float* __restrict__ r1,
                float* __restrict__ r2, const int* __restrict__ flag)
{
    const int f = *flag;
    const int chunk = blockIdx.x & 15;
    const int bh = blockIdx.x >> 4;
    const int b = bh / 12, h = bh % 12;
    const int n0 = chunk * 64;
    __shared__ float w1s[64][65], w2s[64][65];
    __shared__ float ks[64][64];
    const int t = threadIdx.x;
    const int e = t & 63, ng = t >> 6;
    for (int i = t; i < 4096; i += 256) {
        const int d = i >> 6, ee = i & 63;
        w1s[d][ee] = ldin(w1, (size_t)h * 4096 + i, f);
        w2s[d][ee] = ldin(w2, (size_t)h * 4096 + i, f);
    }
    for (int i = t; i < 4096; i += 256) {
        const int nn = i >> 6, dd = i & 63;
        ks[nn][dd] = qkv[((size_t)b * 1024 + n0 + nn) * 2496 + 768 + h * 64 + dd];
    }
    __syncthreads();
    float z1[16], z2[16];
    #pragma unroll
    for (int i = 0; i < 16; i++) { z1[i] = 0.f; z2[i] = 0.f; }
    const int nb = ng * 16;
    for (int dc = 0; dc < 16; ++dc) {
        float w1v[4], w2v[4];
        #pragma unroll
        for (int j = 0; j < 4; ++j) {
            w1v[j] = w1s[dc * 4 + j][e];
            w2v[j] = w2s[dc * 4 + j][e];
        }
        #pragma unroll
        for (int i = 0; i < 16; i++) {
            const float4 k4 = *(const float4*)&ks[nb + i][dc * 4];
            z1[i] += k4.x * w1v[0]; z1[i] += k4.y * w1v[1];
            z1[i] += k4.z * w1v[2]; z1[i] += k4.w * w1v[3];
            z2[i] += k4.x * w2v[0]; z2[i] += k4.y * w2v[1];
            z2[i] += k4.z * w2v[2]; z2[i] += k4.w * w2v[3];
        }
    }
    #pragma unroll
    for (int i = 0; i < 16; i++) {
        const int n = n0 + nb + i;
        const float vv = qkv[((size_t)b * 1024 + n) * 2496 + 1536 + h * 64 + e];
        const float ec = vv * (-1.0f / 3072.0f);
        const float sig = 1.f / (1.f + __expf(-z2[i]));
        const size_t ro = ((size_t)bh * 1024 + n) * 64 + e;
        r1[ro] = ec * z2[i] * sig;
        r2[ro] = ec * z1[i] * (sig * (1.f + z2[i] * (1.f - sig)));
    }
}

// ------------------------------------------------------------------
// x1b: LDS-tiled x1 = (q@wu1)*silu(q@wu2), same structure as zr2;
// stages per-bh wu1,wu2 (fp32 ws buffers); writes hi+lo bf16 xc16.
// ------------------------------------------------------------------
__global__ __launch_bounds__(256)
void x1b_kernel(const float* __restrict__ qkv, const float* __restrict__ wu1,
                const float* __restrict__ wu2, us* __restrict__ xc16)
{
    const int chunk = blockIdx.x & 15;
    const int bh = blockIdx.x >> 4;
    const int b = bh / 12, h = bh % 12;
    const int n0 = chunk * 64;
    __shared__ float w1s[64][65], w2s[64][65];
    __shared__ float qs[64][64];
    const int t = threadIdx.x;
    const int e = t & 63, ng = t >> 6;
    for (int i = t; i < 4096; i += 256) {
        const int d = i >> 6, ee = i & 63;
        w1s[d][ee] = wu1[(size_t)bh * 4096 + i];
        w2s[d][ee] = wu2[(size_t)bh * 4096 + i];
    }
    for (int i = t; i < 4096; i += 256) {
        const int nn = i >> 6, dd = i & 63;
        qs[nn][dd] = qkv[((size_t)b * 1024 + n0 + nn) * 2496 + h * 64 + dd];
    }
    __syncthreads();
    float z1[16], z2[16];
    #pragma unroll
    for (int i = 0; i < 16; i++) { z1[i] = 0.f; z2[i] = 0.f; }
    const int nb = ng * 16;
    for (int dc = 0; dc < 16; ++dc) {
        float w1v[4], w2v[4];
        #pragma unroll
        for (int j = 0; j < 4; ++j) {
            w1v[j] = w1s[dc * 4 + j][e];
            w2v[j] = w2s[dc * 4 + j][e];
        }
        #pragma unroll
        for (int i = 0; i < 16; i++) {
            const float4 k4 = *(const float4*)&qs[nb + i][dc * 4];
            z1[i] += k4.x * w1v[0]; z1[i] += k4.y * w1v[1];
            z1[i] += k4.z * w1v[2]; z1[i] += k4.w * w1v[3];
            z2[i] += k4.x * w2v[0]; z2[i] += k4.y * w2v[1];
            z2[i] += k4.z * w2v[2]; z2[i] += k4.w * w2v[3];
        }
    }
    #pragma unroll
    for (int i = 0; i < 16; i++) {
        const int n = n0 + nb + i;
        const float sig = 1.f / (1.f + __expf(-z2[i]));
        const float val = z1[i] * z2[i] * sig;
        const size_t rb = (size_t)b * 1024 + n;
        const int c = h * 64 + e;
        const us hi = f2bf(val);
        xc16[rb * 1664 + c] = hi;
        xc16[rb * 1664 + 832 + c] = f2bf(val - bf2f(hi));
    }
}

// ------------------------------------------------------------------
// grad stage 1: partial g over a 128-row n-slice. block = (bh, slice s of 8).
// ------------------------------------------------------------------
__global__ __launch_bounds__(256)
void grad_partial(const float* __restrict__ qkv, const float* __restrict__ r1,
                  const float* __restrict__ r2, float* __restrict__ gpart)
{
    const int s = blockIdx.x & 7;
    const int bh = blockIdx.x >> 3;
    const int b = bh / 12, h = bh % 12;
    __shared__ float ks[64][64];
    const int t = threadIdx.x;
    const int e = t & 63, dq = t >> 6;
    float g1[16], g2[16];
    for (int i = 0; i < 16; i++) { g1[i] = 0.f; g2[i] = 0.f; }
    for (int ch = 0; ch < 2; ch++) {
        const int n0 = s * 128 + ch * 64;
        __syncthreads();
        for (int i = t; i < 4096; i += 256) {
            const int nn = i >> 6, dd = i & 63;
            ks[nn][dd] = qkv[((size_t)b * 1024 + n0 + nn) * 2496 + 768 + h * 64 + dd];
        }
        __syncthreads();
        const float* r1p = r1 + ((size_t)bh * 1024 + n0) * 64 + e;
        const float* r2p = r2 + ((size_t)bh * 1024 + n0) * 64 + e;
        for (int nn = 0; nn < 64; nn++) {
            const float rv1 = r1p[nn * 64], rv2 = r2p[nn * 64];
            for (int i = 0; i < 16; i++) {
                const float kv = ks[nn][dq + i * 4];
                g1[i] += kv * rv1; g2[i] += kv * rv2;
            }
        }
    }
    float* gp = gpart + (size_t)blockIdx.x * 8192;
    for (int i = 0; i < 16; i++) {
        gp[(dq + i * 4) * 64 + e] = g1[i];
        gp[4096 + (dq + i * 4) * 64 + e] = g2[i];
    }
}

// ------------------------------------------------------------------
// grad stage 2: sum 8 slices, per-e norm over d, wu = w - g*inv.
// ------------------------------------------------------------------
__global__ __launch_bounds__(256)
void grad_finalize(const float* __restrict__ gpart, const void* __restrict__ w1,
                   const void* __restrict__ w2, float* __restrict__ wu1,
                   float* __restrict__ wu2, const int* __restrict__ flag)
{
    const int f = *flag;
    const int bh = blockIdx.x, h = bh % 12;
    __shared__ float gs[2][64][65];
    __shared__ float inv[2][64];
    const int t = threadIdx.x;
    for (int i = t; i < 4096; i += 256) {
        float a0 = 0.f, a1 = 0.f;
        const float* gp = gpart + (size_t)bh * 8 * 8192;
        for (int s = 0; s < 8; s++) {
            a0 += gp[(size_t)s * 8192 + i];
            a1 += gp[(size_t)s * 8192 + 4096 + i];
        }
        gs[0][i >> 6][i & 63] = a0;
        gs[1][i >> 6][i & 63] = a1;
    }
    __syncthreads();
    if (t < 128) {
        const int w = t >> 6, ee = t & 63;
        float sacc = 0.f;
        for (int d = 0; d < 64; d++) { const float g = gs[w][d][ee]; sacc += g * g; }
        inv[w][ee] = 1.f / (sqrtf(sacc) + 1.f);
    }
    __syncthreads();
    for (int i = t; i < 4096; i += 256) {
        const int d = i >> 6, ee = i & 63;
        const float w1v = ldin(w1, (size_t)h * 4096 + i, f);
        const float w2v = ldin(w2, (size_t)h * 4096 + i, f);
        wu1[(size_t)bh * 4096 + i] = w1v - gs[0][d][ee] * inv[0][ee];
        wu2[(size_t)bh * 4096 + i] = w2v - gs[1][d][ee] * inv[1][ee];
    }
}

// ------------------------------------------------------------------
// Depthwise 3x3 branch. Gradient phase uses all 256 threads:
// one wave per channel (c = t>>6), lane covers (ys,x), 16 y-rows each,
// full 64-lane shuffle reduce.
// ------------------------------------------------------------------
__global__ __launch_bounds__(256)
void dwc_f32(const float* __restrict__ qkv, const void* __restrict__ w3,
             us* __restrict__ xc16, const int* __restrict__ flag)
{
    const int f = *flag;
    __shared__ float qch[4][1026], kch[4][1026], vch[4][1026];
    __shared__ float w3s[4][12];
    const int b = blockIdx.x >> 4, dg = blockIdx.x & 15;
    const int t = threadIdx.x;
    for (int rr = 0; rr < 4; rr++) {
        const int n = t + rr * 256;
        const float* rp = qkv + ((size_t)b * 1024 + n) * 2496 + 2304 + dg * 4;
        for (int c = 0; c < 4; c++) {
            qch[c][n] = rp[c]; kch[c][n] = rp[64 + c]; vch[c][n] = rp[128 + c];
        }
    }
    __syncthreads();
    {
        const int c = t >> 6, l = t & 63;
        const int ysb = l >> 5, x = l & 31;
        float g[9];
        for (int i = 0; i < 9; i++) g[i] = 0.f;
        for (int y = ysb * 16; y < ysb * 16 + 16; y++) {
            const float e = vch[c][y * 32 + x] * (-1.0f / 3072.0f);
            for (int dy = -1; dy <= 1; dy++) {
                const int yy = y + dy;
                if (yy < 0 || yy > 31) continue;
                for (int dx = -1; dx <= 1; dx++) {
                    const int xx = x + dx;
                    if (xx < 0 || xx > 31) continue;
                    g[(dy + 1) * 3 + dx + 1] += kch[c][yy * 32 + xx] * e;
                }
            }
        }
        for (int m = 32; m >= 1; m >>= 1)
            for (int i = 0; i < 9; i++)
                g[i] += __shfl_xor(g[i], m, 64);
        if (l == 0) {
            float s = 0.f;
            for (int i = 0; i < 9; i++) s += g[i] * g[i];
            const float nrm = 1.f / (sqrtf(s) + 1.f);
            const int d = dg * 4 + c;
            for (int i = 0; i < 9; i++)
                w3s[c][i] = ldin(w3, (size_t)d * 9 + i, f) - g[i] * nrm;
        }
    }
    __syncthreads();
    for (int rr = 0; rr < 4; rr++) {
        const int n = t + rr * 256;
        const int y = n >> 5, xx = n & 31;
        for (int cc = 0; cc < 4; cc++) {
            float acc = 0.f;
            for (int ky = 0; ky < 3; ky++) {
                const int yy = y + ky - 1;
                if (yy < 0 || yy > 31) continue;
                for (int kx = 0; kx < 3; kx++) {
                    const int xz = xx + kx - 1;
                    if (xz < 0 || xz > 31) continue;
                    acc += qch[cc][yy * 32 + xz] * w3s[cc][ky * 3 + kx];
                }
            }
            const size_t rb = (size_t)b * 1024 + n;
            const int c = 768 + dg * 4 + cc;
            const us hi = f2bf(acc);
            xc16[rb * 1664 + c] = hi;
            xc16[rb * 1664 + 832 + c] = f2bf(acc - bf2f(hi));
        }
    }
}

// ------------------------------------------------------------------
// ws layout: [flag 256B][Wt 2496x1536 bf16][Pt 768x1664 bf16]
//            [x16 32768x1536 bf16][CB fp32 region]
// CB unit fp32 elems: qkv 2555904 + r1/r2 2*786432 + gpart 786432
//   + wu 2*49152 + xc 851968 = 5,865,472
// ------------------------------------------------------------------
extern "C" void kernel_launch(void* const* d_in, const int* in_sizes, int n_in,
                              void* d_out, int out_size, void* d_ws, size_t ws_size,
                              hipStream_t stream) {
    const void* x      = d_in[0];
    const void* W_qkv  = d_in[1];
    const void* b_qkv  = d_in[2];
    const void* w1     = d_in[3];
    const void* w2     = d_in[4];
    const void* w3     = d_in[5];
    const void* proj_W = d_in[6];
    const void* proj_b = d_in[7];

    int* flag = (int*)d_ws;
    char* wsB = (char*)d_ws + 256;
    us* Wt  = (us*)wsB;
    us* Pt  = (us*)(wsB + (size_t)2496 * 1536 * 2);
    us* x16 = (us*)(wsB + (size_t)2496 * 1536 * 2 + (size_t)768 * 1664 * 2);
    float* base = (float*)((char*)x16 + (size_t)32768 * 1536 * 2);

    const size_t per  = 5865472ULL;  // fp32 elems per CB unit
    const size_t head = 256 + (size_t)2496 * 1536 * 2 + (size_t)768 * 1664 * 2
                            + (size_t)32768 * 1536 * 2;
    int CB = 1;
    for (int cand = 32; cand >= 1; cand >>= 1)
        if (head + per * cand * 4 <= ws_size) { CB = cand; break; }

    float* qkv_c = base;
    float* r1    = qkv_c + (size_t)CB * 1024 * 2496;
    float* r2    = r1    + (size_t)CB * 786432;
    float* gpart = r2    + (size_t)CB * 786432;
    float* wu1   = gpart + (size_t)CB * 786432;
    float* wu2   = wu1   + (size_t)CB * 49152;
    us*    xc16  = (us*)(wu2 + (size_t)CB * 49152);

    detect_dtype<<<1, 256, 0, stream>>>((const us*)x, flag);
    split_rows<<<32768, 256, 0, stream>>>(x, x16, flag, 768);
    transpose_split<<<(768 / 32) * (2496 / 32), 256, 0, stream>>>(
        W_qkv, Wt, 768, 2496, flag);
    transpose_split<<<(832 / 32) * (768 / 32), 256, 0, stream>>>(
        proj_W, Pt, 832, 768, flag);

    const int passes = 32 / CB;
    const int nrows = CB * 1024;
    const int ntm = nrows / 128;
    for (int p = 0; p < passes; p++) {
        const size_t row0 = (size_t)p * CB * 1024;
        mfma_gemm_qkv<<<ntm * 39, 256, 0, stream>>>(
            x16, Wt, b_qkv, qkv_c, flag, row0, ntm);
        zr2_kernel<<<CB * 192, 256, 0, stream>>>(qkv_c, w1, w2, r1, r2, flag);
        grad_partial<<<CB * 96, 256, 0, stream>>>(qkv_c, r1, r2, gpart);
        grad_finalize<<<CB * 12, 256, 0, stream>>>(gpart, w1, w2, wu1, wu2, flag);
        x1b_kernel<<<CB * 192, 256, 0, stream>>>(qkv_c, wu1, wu2, xc16);
        dwc_f32<<<CB * 16, 256, 0, stream>>>(qkv_c, w3, xc16, flag);
        mfma_gemm_proj<<<ntm * 12, 256, 0, stream>>>(
            xc16, Pt, proj_b, d_out, flag, row0, ntm);
    }
}